// Round 2
// baseline (62025.848 us; speedup 1.0000x reference)
//
#include <hip/hip_runtime.h>

#define L 64
#define TLEN 200000
#define CH 528                        // divisible by 8 (replay unroll); 528 % 8 == 0
#define NCH 379                       // ceil(200000/528); 378*528 = 199584
#define LASTLEN (TLEN - (NCH - 1) * CH)   // 416 (divisible by 8)
#define NEGV -10000.0f
#define STARTT 62
#define STOPT 63

// workspace layout (bytes) — total 123052 < 126940 proven available
#define CKPT_OFF 0                          // float[(NCH+1)*L]  = 97280 B
#define M_OFF ((NCH + 1) * L * 4)           // uchar[NCH*L]      = 24256 B
#define ETAG_OFF (M_OFF + NCH * L)          // int[NCH]          = 1516 B

typedef float f32x4 __attribute__((ext_vector_type(4)));

// Compiler-only fence: orders the vsh ds_write before the next step's ds_reads
// in program order. Hardware ordering is the in-order per-wave DS pipe (same
// guarantee replay_chunk has relied on across all passing runs).
#define STEP_BARRIER() __asm__ volatile("" ::: "memory")

// force v_max3_f32 (3-input max, 1 instruction) — reduce 64->1 in ~34 instrs
__device__ __forceinline__ float max3f(float a, float b, float c) {
    float r;
    __asm__("v_max3_f32 %0, %1, %2, %3" : "=v"(r) : "v"(a), "v"(b), "v"(c));
    return r;
}
__device__ __forceinline__ f32x4 vmax3q(f32x4 a, f32x4 b, f32x4 c) {
    f32x4 r;
    r.x = max3f(a.x, b.x, c.x);
    r.y = max3f(a.y, b.y, c.y);
    r.z = max3f(a.z, b.z, c.z);
    r.w = max3f(a.w, b.w, c.w);
    return r;
}

// ---------------------------------------------------------------------------
// Pass 1: exact sequential forward recurrence — SINGLE WAVE, no barriers, no
// atomics. Lane n owns next-tag n and holds T[n][0..63] in 16 PINNED f32x4
// registers (round-1 lesson: without the "+v" asm pin, LLVM rematerializes
// the 16 global loads of the T row inside every step — VGPR_Count=60 and a
// ~2x regression; the pin is load-bearing). Per step:
//   - v[0..15]  arrive via v_readlane SGPR broadcast of vreg (pure VALU path
//     that starts immediately after vreg is produced — hides LDS latency)
//   - v[16..63] arrive via 12 uniform-address ds_read_b128 broadcasts of vsh,
//     ordered after the previous step's single ds_write_b32 by the in-order
//     per-wave DS pipe (no s_barrier, no cross-wave drain).
// Bit-exactness: each score is one RN(v[p]+T[n][p]) exactly as the reference;
// max (incl. v_max3) is order-invariant over finite floats; +feat is rounded
// once at the end: RN(max + f). Checkpoints therefore match the reference
// recurrence bit-for-bit, so the replay kernels are unchanged.
// ---------------------------------------------------------------------------
__global__ __launch_bounds__(64, 1) void k_forward(const float* __restrict__ feats,
                                                   const float* __restrict__ trans,
                                                   float* __restrict__ ckpt) {
    const int n = threadIdx.x;  // 0..63, next-tag owned by this lane

    // T[n][0..63] as 16 named quads — MUST stay register-resident
    const f32x4* t4 = reinterpret_cast<const f32x4*>(trans) + n * 16;
    f32x4 tq0 = t4[0], tq1 = t4[1], tq2 = t4[2], tq3 = t4[3];
    f32x4 tq4 = t4[4], tq5 = t4[5], tq6 = t4[6], tq7 = t4[7];
    f32x4 tq8 = t4[8], tq9 = t4[9], tq10 = t4[10], tq11 = t4[11];
    f32x4 tq12 = t4[12], tq13 = t4[13], tq14 = t4[14], tq15 = t4[15];

#define PIN_TQ()                                                                  \
    __asm__ volatile(""                                                           \
                     : "+v"(tq0), "+v"(tq1), "+v"(tq2), "+v"(tq3), "+v"(tq4),     \
                       "+v"(tq5), "+v"(tq6), "+v"(tq7), "+v"(tq8), "+v"(tq9),     \
                       "+v"(tq10), "+v"(tq11), "+v"(tq12), "+v"(tq13),            \
                       "+v"(tq14), "+v"(tq15))

    PIN_TQ();

    __shared__ __align__(16) float vsh[L];
    const f32x4* vs4 = reinterpret_cast<const f32x4*>(vsh);

    float vreg = (n == STARTT) ? 0.0f : NEGV;  // v_{-1}
    vsh[n] = vreg;
    STEP_BARRIER();

    float fc[8];
#pragma unroll
    for (int j = 0; j < 8; ++j) fc[j] = feats[j * L + n];

#define RL(p) __int_as_float(__builtin_amdgcn_readlane(__float_as_int(vreg), p))

#define FWD_STEP(FEAT)                                                         \
    do {                                                                       \
        /* head: p = 0..15 via readlane broadcast (no LDS dependency) */       \
        const float h0 = RL(0) + tq0.x;                                        \
        const float h1 = RL(1) + tq0.y;                                        \
        const float h2 = RL(2) + tq0.z;                                        \
        const float h3 = RL(3) + tq0.w;                                        \
        const float h4 = RL(4) + tq1.x;                                        \
        const float h5 = RL(5) + tq1.y;                                        \
        const float h6 = RL(6) + tq1.z;                                        \
        const float h7 = RL(7) + tq1.w;                                        \
        const float h8 = RL(8) + tq2.x;                                        \
        const float h9 = RL(9) + tq2.y;                                        \
        const float h10 = RL(10) + tq2.z;                                      \
        const float h11 = RL(11) + tq2.w;                                      \
        const float h12 = RL(12) + tq3.x;                                      \
        const float h13 = RL(13) + tq3.y;                                      \
        const float h14 = RL(14) + tq3.z;                                      \
        const float h15 = RL(15) + tq3.w;                                      \
        const float a0 = max3f(h0, h1, h2);                                    \
        const float a1 = max3f(h3, h4, h5);                                    \
        const float a2 = max3f(h6, h7, h8);                                    \
        const float a3 = max3f(h9, h10, h11);                                  \
        const float a4 = max3f(h12, h13, h14);                                 \
        const float mh = fmaxf(max3f(a0, a1, a2), max3f(a3, a4, h15));         \
        /* tail: p = 16..63 via broadcast ds_read_b128 (conflict-free) */      \
        const f32x4 s4 = vs4[4] + tq4;                                         \
        const f32x4 s5 = vs4[5] + tq5;                                         \
        const f32x4 s6 = vs4[6] + tq6;                                         \
        const f32x4 s7 = vs4[7] + tq7;                                         \
        const f32x4 s8 = vs4[8] + tq8;                                         \
        const f32x4 s9 = vs4[9] + tq9;                                         \
        const f32x4 s10 = vs4[10] + tq10;                                      \
        const f32x4 s11 = vs4[11] + tq11;                                      \
        const f32x4 s12 = vs4[12] + tq12;                                      \
        const f32x4 s13 = vs4[13] + tq13;                                      \
        const f32x4 s14 = vs4[14] + tq14;                                      \
        const f32x4 s15 = vs4[15] + tq15;                                      \
        const f32x4 c0 = vmax3q(s4, s5, s6);                                   \
        const f32x4 c1 = vmax3q(s7, s8, s9);                                   \
        const f32x4 c2 = vmax3q(s10, s11, s12);                                \
        const f32x4 c3 = vmax3q(s13, s14, s15);                                \
        const f32x4 d0 = vmax3q(c0, c1, c2);                                   \
        f32x4 e;                                                               \
        e.x = fmaxf(d0.x, c3.x);                                               \
        e.y = fmaxf(d0.y, c3.y);                                               \
        e.z = fmaxf(d0.z, c3.z);                                               \
        e.w = fmaxf(d0.w, c3.w);                                               \
        const float m = max3f(max3f(e.x, e.y, e.z), e.w, mh);                  \
        vreg = m + (FEAT);                                                     \
        vsh[n] = vreg;                                                         \
        STEP_BARRIER();                                                        \
    } while (0)

    int nextck = 0, cidx = 0;

    for (int tb = 0; tb < TLEN; tb += 8) {
        PIN_TQ();  // keep the T row in VGPRs across the whole loop
        if (tb == nextck) {
            // vreg holds v_{tb-1}; CH % 8 == 0 keeps checkpoint hits at block start
            ckpt[cidx * L + n] = vreg;
            nextck += CH;
            ++cidx;
        }
        float fn_[8];
        const bool more = (tb + 8) < TLEN;
        if (more) {
#pragma unroll
            for (int j = 0; j < 8; ++j) fn_[j] = feats[(tb + 8 + j) * L + n];
        }
        FWD_STEP(fc[0]);
        FWD_STEP(fc[1]);
        FWD_STEP(fc[2]);
        FWD_STEP(fc[3]);
        FWD_STEP(fc[4]);
        FWD_STEP(fc[5]);
        FWD_STEP(fc[6]);
        FWD_STEP(fc[7]);
        if (more) {
#pragma unroll
            for (int j = 0; j < 8; ++j) fc[j] = fn_[j];
        }
    }
    // vreg = v_{199999}
    ckpt[NCH * L + n] = vreg;
#undef FWD_STEP
#undef RL
#undef PIN_TQ
}

// ---------------------------------------------------------------------------
// helpers for the replay kernels (off the critical path, ~0.8 ms total)
// ---------------------------------------------------------------------------
__device__ __forceinline__ void load_trow(const float* __restrict__ trans, int n, float* trow) {
#pragma unroll
    for (int i = 0; i < 16; ++i) {
        const f32x4 q = reinterpret_cast<const f32x4*>(trans)[n * 16 + i];
        trow[4 * i + 0] = q.x;
        trow[4 * i + 1] = q.y;
        trow[4 * i + 2] = q.z;
        trow[4 * i + 3] = q.w;
    }
}

// Bit-exact chunk replay from checkpoint; records backpointers into LDS.
// Single wave per block; in-order DS pipe makes ds_write->ds_read safe with
// only a compiler barrier. Argmax is an in-order strictly-greater scan =>
// first-max, matching jnp.argmax; v matches k_forward bit-for-bit (max is
// order-invariant, +feat monotone-exact).
__device__ __forceinline__ void replay_chunk(const float* __restrict__ feats,
                                             const float* __restrict__ ckpt,
                                             const float* trow, float* vsh,
                                             unsigned char* bpl, int c, int len, int n) {
    float vreg = ckpt[c * L + n];
    vsh[n] = vreg;
    STEP_BARRIER();
    const int base = c * CH;

    float fc[8];
#pragma unroll
    for (int j = 0; j < 8; ++j) fc[j] = feats[(base + j) * L + n];

    for (int sb = 0; sb < len; sb += 8) {
        float fn_[8];
        const bool more = (sb + 8) < len;
        if (more) {
#pragma unroll
            for (int j = 0; j < 8; ++j) fn_[j] = feats[(base + sb + 8 + j) * L + n];
        }
#pragma unroll
        for (int j = 0; j < 8; ++j) {
            float mc[4];
            int ic[4];
#pragma unroll
            for (int g = 0; g < 4; ++g) {
                float m = -INFINITY;
                int idx = g * 16;
#pragma unroll
                for (int r = 0; r < 4; ++r) {
                    const int pb = g * 16 + r * 4;
                    const f32x4 vv = *reinterpret_cast<const f32x4*>(vsh + pb);
                    const float a = vv.x + trow[pb + 0];
                    const float b = vv.y + trow[pb + 1];
                    const float cc = vv.z + trow[pb + 2];
                    const float d = vv.w + trow[pb + 3];
                    if (a > m)  { m = a;  idx = pb + 0; }
                    if (b > m)  { m = b;  idx = pb + 1; }
                    if (cc > m) { m = cc; idx = pb + 2; }
                    if (d > m)  { m = d;  idx = pb + 3; }
                }
                mc[g] = m;
                ic[g] = idx;
            }
            float m = mc[0];
            int idx = ic[0];
            if (mc[1] > m) { m = mc[1]; idx = ic[1]; }
            if (mc[2] > m) { m = mc[2]; idx = ic[2]; }
            if (mc[3] > m) { m = mc[3]; idx = ic[3]; }

            vreg = m + fc[j];
            bpl[(sb + j) * L + n] = (unsigned char)idx;
            vsh[n] = vreg;
            STEP_BARRIER();
        }
        if (more) {
#pragma unroll
            for (int j = 0; j < 8; ++j) fc[j] = fn_[j];
        }
    }
}

// ---------------------------------------------------------------------------
// Pass 2: per-chunk bit-exact replay -> backpointers -> 64-entry chunk map.
// M[c*64+e] = tag at (c*CH - 1) given tag e at the last step of chunk c.
// ---------------------------------------------------------------------------
__global__ __launch_bounds__(64, 1) void k_maps(const float* __restrict__ feats,
                                                const float* __restrict__ trans,
                                                const float* __restrict__ ckpt,
                                                unsigned char* __restrict__ M) {
    const int c = blockIdx.x;
    const int n = threadIdx.x;
    const int len = (c == NCH - 1) ? LASTLEN : CH;

    __shared__ __align__(16) float vsh[L];
    __shared__ unsigned char bpl[CH * L];

    float trow[L];
    load_trow(trans, n, trow);
    replay_chunk(feats, ckpt, trow, vsh, bpl, c, len, n);
    __syncthreads();

    int tag = n;
    for (int s = len - 1; s >= 0; --s) tag = bpl[s * L + tag];
    M[c * L + n] = (unsigned char)tag;
}

// ---------------------------------------------------------------------------
// Pass 3: terminal argmax (bit-exact score) + back-to-front map composition.
// ---------------------------------------------------------------------------
__global__ __launch_bounds__(64, 1) void k_stitch(const float* __restrict__ trans,
                                                  const float* __restrict__ ckpt,
                                                  const unsigned char* __restrict__ M,
                                                  int* __restrict__ etag,
                                                  float* __restrict__ out) {
    const int n = threadIdx.x;
    __shared__ float tsh[L];
    __shared__ int bsh;
    __shared__ __align__(16) unsigned char msh[NCH * L];

    tsh[n] = ckpt[NCH * L + n] + trans[STOPT * L + n];  // terminal[n]
    __syncthreads();
    if (n == 0) {
        float m = tsh[0];
        int b = 0;
        for (int p = 1; p < L; ++p)
            if (tsh[p] > m) { m = tsh[p]; b = p; }  // first-max, like jnp.argmax
        out[0] = m;   // path_score, bit-exact
        bsh = b;
    }
    __syncthreads();

    for (int i = n; i < (NCH * L) / 4; i += L)
        reinterpret_cast<int*>(msh)[i] = reinterpret_cast<const int*>(M)[i];
    __syncthreads();

    if (n == 0) {
        int carry = bsh;  // tag at t = T-1 = end of chunk NCH-1
        for (int c = NCH - 1; c >= 1; --c) {
            etag[c] = carry;
            carry = msh[c * L + carry];
        }
        etag[0] = carry;
    }
}

// ---------------------------------------------------------------------------
// Pass 4: per-chunk replay again, walk backwards from etag[c], emit path.
// Path written as float32 (harness reads the concatenated output as float).
// ---------------------------------------------------------------------------
__global__ __launch_bounds__(64, 1) void k_emit(const float* __restrict__ feats,
                                                const float* __restrict__ trans,
                                                const float* __restrict__ ckpt,
                                                const int* __restrict__ etag,
                                                float* __restrict__ out) {
    const int c = blockIdx.x;
    const int n = threadIdx.x;
    const int len = (c == NCH - 1) ? LASTLEN : CH;

    __shared__ __align__(16) float vsh[L];
    __shared__ unsigned char bpl[CH * L];
    __shared__ unsigned char plc[CH];

    float trow[L];
    load_trow(trans, n, trow);
    replay_chunk(feats, ckpt, trow, vsh, bpl, c, len, n);
    __syncthreads();

    int tag = etag[c];  // uniform; bpl reads below broadcast (same address)
    for (int s = len - 1; s >= 0; --s) {
        if (n == 0) plc[s] = (unsigned char)tag;
        tag = bpl[s * L + tag];
    }
    __syncthreads();

    for (int i = n; i < len; i += L)
        out[1 + c * CH + i] = (float)plc[i];
}

// ---------------------------------------------------------------------------
extern "C" void kernel_launch(void* const* d_in, const int* in_sizes, int n_in,
                              void* d_out, int out_size, void* d_ws, size_t ws_size,
                              hipStream_t stream) {
    const float* feats = (const float*)d_in[0];   // (1, T, L) fp32
    const float* trans = (const float*)d_in[1];   // (L, L) fp32
    float* out = (float*)d_out;                   // [score, path(T) as float]
    char* ws = (char*)d_ws;
    float* ckpt = (float*)(ws + CKPT_OFF);
    unsigned char* M = (unsigned char*)(ws + M_OFF);
    int* etag = (int*)(ws + ETAG_OFF);

    hipLaunchKernelGGL(k_forward, dim3(1), dim3(64), 0, stream, feats, trans, ckpt);
    hipLaunchKernelGGL(k_maps, dim3(NCH), dim3(64), 0, stream, feats, trans, ckpt, M);
    hipLaunchKernelGGL(k_stitch, dim3(1), dim3(64), 0, stream, trans, ckpt, M, etag, out);
    hipLaunchKernelGGL(k_emit, dim3(NCH), dim3(64), 0, stream, feats, trans, ckpt, etag, out);
}

// Round 3
// 30154.150 us; speedup vs baseline: 2.0570x; 2.0570x over previous
//
#include <hip/hip_runtime.h>

#define L 64
#define TLEN 200000
#define CH 528                        // divisible by 6 (fwd unroll) and 8 (replay unroll)
#define NCH 379                       // ceil(200000/528); 378*528 = 199584
#define LASTLEN (TLEN - (NCH - 1) * CH)   // 416 (divisible by 8)
#define MAINT 199992                  // 6*33332, main-loop trip; tail = 8 steps
#define NEGV -10000.0f
#define STARTT 62
#define STOPT 63

// workspace layout (bytes) — total 123052 < 126940 proven available
#define CKPT_OFF 0                          // float[(NCH+1)*L]  = 97280 B
#define M_OFF ((NCH + 1) * L * 4)           // uchar[NCH*L]      = 24256 B
#define ETAG_OFF (M_OFF + NCH * L)          // int[NCH]          = 1516 B

typedef float f32x4 __attribute__((ext_vector_type(4)));

// Drained barrier: used ONCE at init (ordinary ds_writes must be visible).
#define WAVE_BARRIER() __asm__ volatile("s_waitcnt lgkmcnt(0)\ns_barrier" ::: "memory")
// Per-step barrier WITHOUT the lgkmcnt(0) drain. Hypothesis under test: the
// per-step ds_max is issued ~40+cy before any post-barrier read from another
// SIMD reaches the (near-empty) LDS pipe, so completion order is safe without
// draining. If this races, the harness fails loudly (absmax) and we revert.
// NOTE: each wave's OWN data dependencies (its ds_reads, and — because DS ops
// complete in issue order per wave — its earlier atomic) are still covered by
// the compiler-inserted lgkmcnt(N) before first use of read data.
#define FAST_BARRIER() __asm__ volatile("s_barrier" ::: "memory")
#define STEP_BARRIER() __asm__ volatile("" ::: "memory")

// force v_max3_f32 (3-input max, 1 instruction); max is order-invariant over
// finite floats so the tree below is bit-identical to the pairwise version.
__device__ __forceinline__ float max3f(float a, float b, float c) {
    float r;
    __asm__("v_max3_f32 %0, %1, %2, %3" : "=v"(r) : "v"(a), "v"(b), "v"(c));
    return r;
}

// ---------------------------------------------------------------------------
// Pass 1: exact sequential forward recurrence (the critical path).
// 4 waves (256 threads), p-split: wave w owns prev-tags [16w,16w+16).
// Each step: broadcast-read own v-slice, partial max, +feat (exact: RN is
// monotone so max_w RN(pm_w+f) == RN(max pm + f)), ds_max_f32 atomic into the
// next v-buffer, one barrier. Triple-buffered v: step s reads buf s%3,
// atomics into (s+1)%3, wave0 resets (s+2)%3 to -inf. The single barrier
// orders all hazards (issue-order side; completion-order is the no-drain
// hypothesis above).
// ---------------------------------------------------------------------------
__global__ __launch_bounds__(256, 1) void k_forward(const float* __restrict__ feats,
                                                    const float* __restrict__ trans,
                                                    float* __restrict__ ckpt) {
    const int tid = threadIdx.x;
    const int n = tid & 63;   // next-tag owned by this lane
    const int w = tid >> 6;   // wave id = p-slice

    // T[n][16w .. 16w+16) — 16 floats, 4 quads; pin keeps them VGPR-resident
    // (verified in round 0: VGPR_Count=28 with this exact pattern).
    const f32x4* t4 = reinterpret_cast<const f32x4*>(trans) + n * 16 + w * 4;
    f32x4 q0 = t4[0], q1 = t4[1], q2 = t4[2], q3 = t4[3];
    __asm__ volatile("" : "+v"(q0), "+v"(q1), "+v"(q2), "+v"(q3));

    __shared__ __align__(16) float vbuf[3][L];

    vbuf[0][n] = (n == STARTT) ? 0.0f : NEGV;  // v_{-1}; same value from all waves
    vbuf[1][n] = -INFINITY;                    // receives step-0 atomics
    vbuf[2][n] = -INFINITY;
    WAVE_BARRIER();

    float fc[6];
#pragma unroll
    for (int j = 0; j < 6; ++j) fc[j] = feats[j * L + n];

    int nextck = 0, cidx = 0;

#define FWD_STEP(RD, WR, RS, FEAT)                                            \
    do {                                                                      \
        if (w == 0) vbuf[RS][n] = -INFINITY;                                  \
        const f32x4 va0 = *reinterpret_cast<const f32x4*>(&vbuf[RD][16 * w + 0]);  \
        const f32x4 va1 = *reinterpret_cast<const f32x4*>(&vbuf[RD][16 * w + 4]);  \
        const f32x4 va2 = *reinterpret_cast<const f32x4*>(&vbuf[RD][16 * w + 8]);  \
        const f32x4 va3 = *reinterpret_cast<const f32x4*>(&vbuf[RD][16 * w + 12]); \
        const f32x4 s0 = va0 + q0, s1 = va1 + q1, s2 = va2 + q2, s3 = va3 + q3;    \
        const float m0 = max3f(fmaxf(s0.x, s0.y), s0.z, s0.w);                \
        const float m1 = max3f(fmaxf(s1.x, s1.y), s1.z, s1.w);                \
        const float m2 = max3f(fmaxf(s2.x, s2.y), s2.z, s2.w);                \
        const float m3 = max3f(fmaxf(s3.x, s3.y), s3.z, s3.w);                \
        const float cand = fmaxf(max3f(m0, m1, m2), m3) + (FEAT);             \
        __hip_atomic_fetch_max(&vbuf[WR][n], cand, __ATOMIC_RELAXED,          \
                               __HIP_MEMORY_SCOPE_WORKGROUP);                 \
        FAST_BARRIER();                                                       \
    } while (0)

    for (int tb = 0; tb < MAINT; tb += 6) {
        if (tb == nextck) {
            // vbuf[0] holds v_{tb-1} (tb%3==0 always; 528%6==0 keeps hits aligned)
            if (w == 0) ckpt[cidx * L + n] = vbuf[0][n];
            nextck += CH;
            ++cidx;
        }
        float fn_[6];
        const bool more = (tb + 6) < MAINT;
        if (more) {
#pragma unroll
            for (int j = 0; j < 6; ++j) fn_[j] = feats[(tb + 6 + j) * L + n];
        }
        FWD_STEP(0, 1, 2, fc[0]);
        FWD_STEP(1, 2, 0, fc[1]);
        FWD_STEP(2, 0, 1, fc[2]);
        FWD_STEP(0, 1, 2, fc[3]);
        FWD_STEP(1, 2, 0, fc[4]);
        FWD_STEP(2, 0, 1, fc[5]);
        if (more) {
#pragma unroll
            for (int j = 0; j < 6; ++j) fc[j] = fn_[j];
        }
    }

    // tail: steps 199992..199999 (MAINT%3==0, so the rotation continues)
    float ft[8];
#pragma unroll
    for (int j = 0; j < 8; ++j) ft[j] = feats[(MAINT + j) * L + n];
    FWD_STEP(0, 1, 2, ft[0]);
    FWD_STEP(1, 2, 0, ft[1]);
    FWD_STEP(2, 0, 1, ft[2]);
    FWD_STEP(0, 1, 2, ft[3]);
    FWD_STEP(1, 2, 0, ft[4]);
    FWD_STEP(2, 0, 1, ft[5]);
    FWD_STEP(0, 1, 2, ft[6]);
    FWD_STEP(1, 2, 0, ft[7]);
    // v_{199999} lives in vbuf[200000 % 3] = vbuf[2]
    if (w == 0) ckpt[NCH * L + n] = vbuf[2][n];
#undef FWD_STEP
}

// ---------------------------------------------------------------------------
// helpers for the replay kernels (off the critical path, ~0.8 ms total)
// ---------------------------------------------------------------------------
__device__ __forceinline__ void load_trow(const float* __restrict__ trans, int n, float* trow) {
#pragma unroll
    for (int i = 0; i < 16; ++i) {
        const f32x4 q = reinterpret_cast<const f32x4*>(trans)[n * 16 + i];
        trow[4 * i + 0] = q.x;
        trow[4 * i + 1] = q.y;
        trow[4 * i + 2] = q.z;
        trow[4 * i + 3] = q.w;
    }
}

// Bit-exact chunk replay from checkpoint; records backpointers into LDS.
// Single wave per block; in-order DS pipe makes ds_write->ds_read safe with
// only a compiler barrier. Argmax is an in-order strictly-greater scan =>
// first-max, matching jnp.argmax; v matches k_forward bit-for-bit (max is
// order-invariant, +feat monotone-exact).
__device__ __forceinline__ void replay_chunk(const float* __restrict__ feats,
                                             const float* __restrict__ ckpt,
                                             const float* trow, float* vsh,
                                             unsigned char* bpl, int c, int len, int n) {
    float vreg = ckpt[c * L + n];
    vsh[n] = vreg;
    STEP_BARRIER();
    const int base = c * CH;

    float fc[8];
#pragma unroll
    for (int j = 0; j < 8; ++j) fc[j] = feats[(base + j) * L + n];

    for (int sb = 0; sb < len; sb += 8) {
        float fn_[8];
        const bool more = (sb + 8) < len;
        if (more) {
#pragma unroll
            for (int j = 0; j < 8; ++j) fn_[j] = feats[(base + sb + 8 + j) * L + n];
        }
#pragma unroll
        for (int j = 0; j < 8; ++j) {
            float mc[4];
            int ic[4];
#pragma unroll
            for (int g = 0; g < 4; ++g) {
                float m = -INFINITY;
                int idx = g * 16;
#pragma unroll
                for (int r = 0; r < 4; ++r) {
                    const int pb = g * 16 + r * 4;
                    const f32x4 vv = *reinterpret_cast<const f32x4*>(vsh + pb);
                    const float a = vv.x + trow[pb + 0];
                    const float b = vv.y + trow[pb + 1];
                    const float cc = vv.z + trow[pb + 2];
                    const float d = vv.w + trow[pb + 3];
                    if (a > m)  { m = a;  idx = pb + 0; }
                    if (b > m)  { m = b;  idx = pb + 1; }
                    if (cc > m) { m = cc; idx = pb + 2; }
                    if (d > m)  { m = d;  idx = pb + 3; }
                }
                mc[g] = m;
                ic[g] = idx;
            }
            float m = mc[0];
            int idx = ic[0];
            if (mc[1] > m) { m = mc[1]; idx = ic[1]; }
            if (mc[2] > m) { m = mc[2]; idx = ic[2]; }
            if (mc[3] > m) { m = mc[3]; idx = ic[3]; }

            vreg = m + fc[j];
            bpl[(sb + j) * L + n] = (unsigned char)idx;
            vsh[n] = vreg;
            STEP_BARRIER();
        }
        if (more) {
#pragma unroll
            for (int j = 0; j < 8; ++j) fc[j] = fn_[j];
        }
    }
}

// ---------------------------------------------------------------------------
// Pass 2: per-chunk bit-exact replay -> backpointers -> 64-entry chunk map.
// M[c*64+e] = tag at (c*CH - 1) given tag e at the last step of chunk c.
// ---------------------------------------------------------------------------
__global__ __launch_bounds__(64, 1) void k_maps(const float* __restrict__ feats,
                                                const float* __restrict__ trans,
                                                const float* __restrict__ ckpt,
                                                unsigned char* __restrict__ M) {
    const int c = blockIdx.x;
    const int n = threadIdx.x;
    const int len = (c == NCH - 1) ? LASTLEN : CH;

    __shared__ __align__(16) float vsh[L];
    __shared__ unsigned char bpl[CH * L];

    float trow[L];
    load_trow(trans, n, trow);
    replay_chunk(feats, ckpt, trow, vsh, bpl, c, len, n);
    __syncthreads();

    int tag = n;
    for (int s = len - 1; s >= 0; --s) tag = bpl[s * L + tag];
    M[c * L + n] = (unsigned char)tag;
}

// ---------------------------------------------------------------------------
// Pass 3: terminal argmax (bit-exact score) + back-to-front map composition.
// ---------------------------------------------------------------------------
__global__ __launch_bounds__(64, 1) void k_stitch(const float* __restrict__ trans,
                                                  const float* __restrict__ ckpt,
                                                  const unsigned char* __restrict__ M,
                                                  int* __restrict__ etag,
                                                  float* __restrict__ out) {
    const int n = threadIdx.x;
    __shared__ float tsh[L];
    __shared__ int bsh;
    __shared__ __align__(16) unsigned char msh[NCH * L];

    tsh[n] = ckpt[NCH * L + n] + trans[STOPT * L + n];  // terminal[n]
    __syncthreads();
    if (n == 0) {
        float m = tsh[0];
        int b = 0;
        for (int p = 1; p < L; ++p)
            if (tsh[p] > m) { m = tsh[p]; b = p; }  // first-max, like jnp.argmax
        out[0] = m;   // path_score, bit-exact
        bsh = b;
    }
    __syncthreads();

    for (int i = n; i < (NCH * L) / 4; i += L)
        reinterpret_cast<int*>(msh)[i] = reinterpret_cast<const int*>(M)[i];
    __syncthreads();

    if (n == 0) {
        int carry = bsh;  // tag at t = T-1 = end of chunk NCH-1
        for (int c = NCH - 1; c >= 1; --c) {
            etag[c] = carry;
            carry = msh[c * L + carry];
        }
        etag[0] = carry;
    }
}

// ---------------------------------------------------------------------------
// Pass 4: per-chunk replay again, walk backwards from etag[c], emit path.
// Path written as float32 (harness reads the concatenated output as float).
// ---------------------------------------------------------------------------
__global__ __launch_bounds__(64, 1) void k_emit(const float* __restrict__ feats,
                                                const float* __restrict__ trans,
                                                const float* __restrict__ ckpt,
                                                const int* __restrict__ etag,
                                                float* __restrict__ out) {
    const int c = blockIdx.x;
    const int n = threadIdx.x;
    const int len = (c == NCH - 1) ? LASTLEN : CH;

    __shared__ __align__(16) float vsh[L];
    __shared__ unsigned char bpl[CH * L];
    __shared__ unsigned char plc[CH];

    float trow[L];
    load_trow(trans, n, trow);
    replay_chunk(feats, ckpt, trow, vsh, bpl, c, len, n);
    __syncthreads();

    int tag = etag[c];  // uniform; bpl reads below broadcast (same address)
    for (int s = len - 1; s >= 0; --s) {
        if (n == 0) plc[s] = (unsigned char)tag;
        tag = bpl[s * L + tag];
    }
    __syncthreads();

    for (int i = n; i < len; i += L)
        out[1 + c * CH + i] = (float)plc[i];
}

// ---------------------------------------------------------------------------
extern "C" void kernel_launch(void* const* d_in, const int* in_sizes, int n_in,
                              void* d_out, int out_size, void* d_ws, size_t ws_size,
                              hipStream_t stream) {
    const float* feats = (const float*)d_in[0];   // (1, T, L) fp32
    const float* trans = (const float*)d_in[1];   // (L, L) fp32
    float* out = (float*)d_out;                   // [score, path(T) as float]
    char* ws = (char*)d_ws;
    float* ckpt = (float*)(ws + CKPT_OFF);
    unsigned char* M = (unsigned char*)(ws + M_OFF);
    int* etag = (int*)(ws + ETAG_OFF);

    hipLaunchKernelGGL(k_forward, dim3(1), dim3(256), 0, stream, feats, trans, ckpt);
    hipLaunchKernelGGL(k_maps, dim3(NCH), dim3(64), 0, stream, feats, trans, ckpt, M);
    hipLaunchKernelGGL(k_stitch, dim3(1), dim3(64), 0, stream, trans, ckpt, M, etag, out);
    hipLaunchKernelGGL(k_emit, dim3(NCH), dim3(64), 0, stream, feats, trans, ckpt, etag, out);
}